// Round 6
// baseline (464.421 us; speedup 1.0000x reference)
//
#include <hip/hip_runtime.h>
#include <hip/hip_bf16.h>

typedef unsigned short u16;
typedef __attribute__((ext_vector_type(8))) short short8;
typedef __attribute__((ext_vector_type(4))) short short4v;
typedef __attribute__((ext_vector_type(4))) float f32x4;

#define NEGV -1000000000000000.0f
#define SBAR() asm volatile("s_barrier" ::: "memory")

__device__ __forceinline__ u16 f2bf(float f) {
  unsigned u = __float_as_uint(f);
  unsigned r = (u + 0x7FFFu + ((u >> 16) & 1u)) >> 16;
  return (u16)r;
}
__device__ __forceinline__ float bf2f(u16 s) {
  return __uint_as_float(((unsigned)s) << 16);
}
__device__ __forceinline__ void lds16(const void* g, void* l) {
  __builtin_amdgcn_global_load_lds((const __attribute__((address_space(1))) void*)g,
                                   (__attribute__((address_space(3))) void*)l,
                                   16, 0, 0);
}

// ============ final GEMM: out = Wrb(512x2048) @ Oflat(65536x2048)^T =========
// BM=BN=128, BK=32, 256 thr (4 waves 2x2, 64x64/wave). Quad-buffered A,B
// (66KB LDS) -> 2 blocks/CU for cross-block overlap. Per tile: stage t+2,
// vmcnt(4) (drains t+1, never 0), one barrier, 8 ds_read, 16 MFMA.
// XCD grouping: 4 m-blocks sharing a B-panel get bids = xcd + 8k (same XCD).
__global__ __launch_bounds__(256, 2) void gemm_w(const u16* __restrict__ A,
                                                 const u16* __restrict__ B,
                                                 float* __restrict__ out) {
  extern __shared__ u16 lds[];  // A bufs [4][64rows*... ] 32KB | B bufs 32KB | epilogue f32
  const int bid = blockIdx.x;
  const int xcd = bid & 7;
  const int k = bid >> 3;       // 0..255
  const int nl = k >> 2;        // 0..63: n-tile within xcd
  const int m0 = (k & 3) * 128;
  const int nf = (xcd * 64 + nl) * 128;  // flat n0 (b = nf>>10, c0 = nf&1023)
  const int tid = threadIdx.x;
  const int lane = tid & 63;
  const int w = tid >> 6;
  const int wr = w >> 1, wc = w & 1;
  const int fro = lane & 15, hi = lane >> 4;
  const int srow = tid >> 2;    // stage row 0..63
  const int sslot = tid & 3;    // stage 16B slot

  const u16* Ag = A + (size_t)m0 * 2048;
  const u16* Bg = B + (size_t)nf * 2048;
  const int rA = wr * 64 + fro;
  const int rB = wc * 64 + fro;

  f32x4 acc[4][4] = {};

// stage one 128x32 tile (8KB) into buffer lp: 2 x global_load_lds per thread.
// source 16B-slot pre-swizzled by row&3 (rule 21: linear LDS dest).
#define STG(gp, k0, lp)                                                        \
  {                                                                            \
    lds16((gp) + (size_t)srow * 2048 + (k0) + ((sslot ^ (srow & 3)) << 3),     \
          (u16*)(lp) + tid * 8);                                               \
    lds16((gp) + (size_t)(64 + srow) * 2048 + (k0) +                           \
              ((sslot ^ (srow & 3)) << 3),                                     \
          (u16*)(lp) + 2048 + tid * 8);                                        \
  }
// fragment read: row-major [128][32], swizzled slot = hi ^ (row&3)
#define RDF(lp, row)                                                           \
  (*(const short8*)&((const u16*)(lp))[(size_t)(row) * 32 +                    \
                                       ((hi ^ ((row) & 3)) << 3)])

  // prologue: tiles 0,1
  STG(Ag, 0, lds);                 // A t0 -> Abuf0
  STG(Bg, 0, lds + 16384);         // B t0 -> Bbuf0
  STG(Ag, 32, lds + 4096);         // A t1 -> Abuf1
  STG(Bg, 32, lds + 16384 + 4096); // B t1 -> Bbuf1
  asm volatile("s_waitcnt vmcnt(4)" ::: "memory");  // t0 complete
  SBAR();

  for (int t = 0; t < 64; ++t) {
    const int q2 = (t + 2) & 3;
    const int kk = (t < 62 ? t + 2 : 63) * 32;
    STG(Ag, kk, lds + q2 * 4096);
    STG(Bg, kk, lds + 16384 + q2 * 4096);
    asm volatile("s_waitcnt vmcnt(4)" ::: "memory");  // drain t+1, keep t+2
    SBAR();
    const u16* La = lds + (t & 3) * 4096;
    const u16* Lb = lds + 16384 + (t & 3) * 4096;
    short8 af[4], bf[4];
#pragma unroll
    for (int i = 0; i < 4; ++i) af[i] = RDF(La, rA + i * 16);
#pragma unroll
    for (int j = 0; j < 4; ++j) bf[j] = RDF(Lb, rB + j * 16);
    __builtin_amdgcn_s_setprio(1);
#pragma unroll
    for (int i = 0; i < 4; ++i)
#pragma unroll
      for (int j = 0; j < 4; ++j)
        acc[i][j] =
            __builtin_amdgcn_mfma_f32_16x16x32_bf16(af[i], bf[j], acc[i][j], 0, 0, 0);
    __builtin_amdgcn_s_setprio(0);
  }
  asm volatile("s_waitcnt vmcnt(0)" ::: "memory");
  SBAR();

  // ---- coalesced epilogue via LDS f32 [128][132]
  float* Lf = (float*)lds;
#pragma unroll
  for (int i = 0; i < 4; ++i)
#pragma unroll
    for (int j = 0; j < 4; ++j) {
      const int col = wc * 64 + j * 16 + fro;
#pragma unroll
      for (int g = 0; g < 4; ++g)
        Lf[(wr * 64 + i * 16 + hi * 4 + g) * 132 + col] = acc[i][j][g];
    }
  __syncthreads();
  const int row = tid >> 1;
  const int ch = (tid & 1) * 64;
  float* orow = out + (size_t)(nf >> 10) * 524288 + (size_t)(m0 + row) * 1024 +
                (nf & 1023) + ch;
#pragma unroll
  for (int q = 0; q < 16; ++q)
    *(float4*)(orow + q * 4) = *(float4*)&Lf[row * 132 + ch + q * 4];
#undef STG
#undef RDF
}

// ============ T-GEMM: C_un = EunT(128x1024) @ Corig(512x1024)^T, then
// Tt[b][d][j] = C_un[j][d] / csum[b][j]  (transposed scaled store) ===========
__global__ __launch_bounds__(256) void gemm_t(const u16* __restrict__ A,
                                              const u16* __restrict__ B,
                                              const float* __restrict__ csum,
                                              u16* __restrict__ Tt) {
  __shared__ u16 As[128 * 64];
  __shared__ u16 Bs[128 * 64];
  const int b = blockIdx.z;
  const int n0 = blockIdx.y * 128;
  const u16* Ab = A + (size_t)b * 131072;
  const u16* Bb = B + (size_t)b * 524288;
  const int t = threadIdx.x;
  const int lane = t & 63;
  const int w = t >> 6;
  const int wr = w >> 1, wc = w & 1;
  const int srow = lane >> 3;
  const int scol = (lane & 7) * 8;

  f32x4 acc[4][4] = {};

  for (int k0 = 0; k0 < 1024; k0 += 64) {
    __syncthreads();
#pragma unroll
    for (int qq = 0; qq < 4; ++qq) {
      const int q = w * 4 + qq;
      const int r = q * 8 + srow;
      lds16(Ab + (size_t)r * 1024 + k0 + scol, &As[q * 512]);
      lds16(Bb + (size_t)(n0 + r) * 1024 + k0 + scol, &Bs[q * 512]);
    }
    __syncthreads();
#pragma unroll
    for (int ks = 0; ks < 2; ++ks) {
      short8 af[4], bg[4];
      const int fro = lane & 15;
      const int k8 = ks * 32 + (lane >> 4) * 8;
#pragma unroll
      for (int i = 0; i < 4; ++i)
        af[i] = *(const short8*)&As[(wr * 64 + i * 16 + fro) * 64 + k8];
#pragma unroll
      for (int i = 0; i < 4; ++i)
        bg[i] = *(const short8*)&Bs[(wc * 64 + i * 16 + fro) * 64 + k8];
#pragma unroll
      for (int i = 0; i < 4; ++i)
#pragma unroll
        for (int j = 0; j < 4; ++j)
          acc[i][j] =
              __builtin_amdgcn_mfma_f32_16x16x32_bf16(af[i], bg[j], acc[i][j], 0, 0, 0);
    }
  }

  const int col = lane & 15;
  const int r4 = (lane >> 4) * 4;
#pragma unroll
  for (int i = 0; i < 4; ++i)
#pragma unroll
    for (int g = 0; g < 4; ++g) {
      const int rr = wr * 64 + i * 16 + r4 + g;  // j index
      const float inv = 1.f / csum[b * 128 + rr];
#pragma unroll
      for (int j = 0; j < 4; ++j) {
        const int cc = n0 + wc * 64 + j * 16 + col;  // d index
        Tt[(size_t)b * 65536 + (size_t)cc * 128 + rr] = f2bf(acc[i][j][g] * inv);
      }
    }
}

// ============ S-GEMM + fused dual softmax + transposed-Eun epilogue =========
__global__ __launch_bounds__(256) void gemm_s(
    const u16* __restrict__ A, const u16* __restrict__ Bq,
    const float* __restrict__ cb, const float* __restrict__ qb,
    const float* __restrict__ cmask, const float* __restrict__ qmask,
    u16* __restrict__ Sbar, u16* __restrict__ EunT, float* __restrict__ csum) {
  __shared__ u16 As[128 * 64];
  __shared__ u16 Bs[128 * 64];
  __shared__ u16 Lt[128][136];
  __shared__ float rmaxs[2][128];
  __shared__ float rsums[2][128];
  __shared__ float cparts[2][128];
  const int b = blockIdx.z;
  const int m0 = blockIdx.x * 128;
  const u16* Ab = A + (size_t)b * 2097152;
  const u16* Bb = Bq + (size_t)b * 65536;
  const int t = threadIdx.x;
  const int lane = t & 63;
  const int w = t >> 6;
  const int wr = w >> 1, wc = w & 1;
  const int srow = lane >> 3;
  const int scol = (lane & 7) * 8;

  f32x4 acc[4][4] = {};

  for (int k0 = 0; k0 < 512; k0 += 64) {
    __syncthreads();
#pragma unroll
    for (int qq = 0; qq < 4; ++qq) {
      const int q = w * 4 + qq;
      const int r = q * 8 + srow;
      lds16(Ab + (size_t)(m0 + r) * 2048 + k0 + scol, &As[q * 512]);
      lds16(Bb + (size_t)r * 512 + k0 + scol, &Bs[q * 512]);
    }
    __syncthreads();
#pragma unroll
    for (int ks = 0; ks < 2; ++ks) {
      short8 af[4], bg[4];
      const int fro = lane & 15;
      const int k8 = ks * 32 + (lane >> 4) * 8;
#pragma unroll
      for (int i = 0; i < 4; ++i)
        af[i] = *(const short8*)&As[(wr * 64 + i * 16 + fro) * 64 + k8];
#pragma unroll
      for (int i = 0; i < 4; ++i)
        bg[i] = *(const short8*)&Bs[(wc * 64 + i * 16 + fro) * 64 + k8];
#pragma unroll
      for (int i = 0; i < 4; ++i)
#pragma unroll
        for (int j = 0; j < 4; ++j)
          acc[i][j] =
              __builtin_amdgcn_mfma_f32_16x16x32_bf16(af[i], bg[j], acc[i][j], 0, 0, 0);
    }
  }

  const int fro = lane & 15;
  const int hi = lane >> 4;
  float qv[4], qbv[4];
#pragma unroll
  for (int j = 0; j < 4; ++j) {
    const int cc = wc * 64 + j * 16 + fro;
    qv[j] = qmask[b * 128 + cc];
    qbv[j] = qb[b * 128 + cc];
  }
  float colp[4] = {0.f, 0.f, 0.f, 0.f};
#pragma unroll
  for (int i = 0; i < 4; ++i)
#pragma unroll
    for (int g = 0; g < 4; ++g) {
      const int rl = wr * 64 + i * 16 + hi * 4 + g;
      const float rb = cb[b * 1024 + m0 + rl];
      const float cv = cmask[b * 1024 + m0 + rl];
      const float coff = NEGV * (1.f - cv);
#pragma unroll
      for (int j = 0; j < 4; ++j) {
        const float v = acc[i][j][g] + rb + qbv[j];
        acc[i][j][g] = v;
        const float e = __expf(v * cv + coff);
        Lt[wc * 64 + j * 16 + fro][rl] = f2bf(e);
        colp[j] += e;
      }
    }
#pragma unroll
  for (int j = 0; j < 4; ++j) {
    colp[j] += __shfl_xor(colp[j], 16);
    colp[j] += __shfl_xor(colp[j], 32);
  }
  if (hi == 0)
#pragma unroll
    for (int j = 0; j < 4; ++j) cparts[wr][wc * 64 + j * 16 + fro] = colp[j];
  float rtmp[4][4];
#pragma unroll
  for (int i = 0; i < 4; ++i)
#pragma unroll
    for (int g = 0; g < 4; ++g) {
      float m = -3.4e38f;
#pragma unroll
      for (int j = 0; j < 4; ++j) {
        const float xm = acc[i][j][g] * qv[j] + NEGV * (1.f - qv[j]);
        acc[i][j][g] = xm;
        m = fmaxf(m, xm);
      }
#pragma unroll
      for (int o = 8; o; o >>= 1) m = fmaxf(m, __shfl_xor(m, o));
      rtmp[i][g] = m;
    }
  if (fro == 0)
#pragma unroll
    for (int i = 0; i < 4; ++i)
#pragma unroll
      for (int g = 0; g < 4; ++g)
        rmaxs[wc][wr * 64 + i * 16 + hi * 4 + g] = rtmp[i][g];
  __syncthreads();
  if (t < 128) atomicAdd(&csum[b * 128 + t], cparts[0][t] + cparts[1][t]);
  {
    const int jr = t >> 1;
    const int ih = (t & 1) * 64;
    u16* dst = EunT + (size_t)b * 131072 + (size_t)jr * 1024 + m0 + ih;
#pragma unroll
    for (int s = 0; s < 8; ++s)
      *(short8*)(dst + s * 8) = *(const short8*)&Lt[jr][ih + s * 8];
  }
#pragma unroll
  for (int i = 0; i < 4; ++i)
#pragma unroll
    for (int g = 0; g < 4; ++g) {
      const int rl = wr * 64 + i * 16 + hi * 4 + g;
      const float M = fmaxf(rmaxs[0][rl], rmaxs[1][rl]);
      float s = 0.f;
#pragma unroll
      for (int j = 0; j < 4; ++j) {
        const float p = __expf(acc[i][j][g] - M);
        acc[i][j][g] = p;
        s += p;
      }
#pragma unroll
      for (int o = 8; o; o >>= 1) s += __shfl_xor(s, o);
      rtmp[i][g] = s;
    }
  if (fro == 0)
#pragma unroll
    for (int i = 0; i < 4; ++i)
#pragma unroll
      for (int g = 0; g < 4; ++g)
        rsums[wc][wr * 64 + i * 16 + hi * 4 + g] = rtmp[i][g];
  __syncthreads();
#pragma unroll
  for (int i = 0; i < 4; ++i)
#pragma unroll
    for (int g = 0; g < 4; ++g) {
      const int rl = wr * 64 + i * 16 + hi * 4 + g;
      const float inv = 1.f / (rsums[0][rl] + rsums[1][rl]);
#pragma unroll
      for (int j = 0; j < 4; ++j)
        Sbar[((size_t)b * 1024 + m0 + rl) * 128 + wc * 64 + j * 16 + fro] =
            f2bf(acc[i][j][g] * inv);
    }
}

// ============ merged A+Bm GEMM (shared A=Sbar), vectorized LDS epilogue =====
__global__ __launch_bounds__(256) void gemm_ab(const u16* __restrict__ Sbar,
                                               const u16* __restrict__ Qo,
                                               const u16* __restrict__ Tt,
                                               u16* __restrict__ O) {
  __shared__ u16 sh[3 * 128 * 64];
  u16* As = sh;
  u16* Bq = sh + 8192;
  u16* Bt = sh + 16384;
  const int b = blockIdx.z;
  const int m0 = blockIdx.x * 128;
  const int dcol = blockIdx.y * 128;
  const u16* Ab = Sbar + (size_t)b * 131072;
  const u16* Qg = Qo + (size_t)b * 65536 + (size_t)dcol * 128;
  const u16* Tg = Tt + (size_t)b * 65536 + (size_t)dcol * 128;
  const int t = threadIdx.x;
  const int lane = t & 63;
  const int w = t >> 6;
  const int wr = w >> 1, wc = w & 1;
  const int srow = lane >> 3;
  const int scol = (lane & 7) * 8;
  const int fro = lane & 15;
  const int hi = lane >> 4;

  f32x4 aa[4][4] = {};
  f32x4 ab[4][4] = {};

  for (int k0 = 0; k0 < 128; k0 += 64) {
    __syncthreads();
#pragma unroll
    for (int qq = 0; qq < 4; ++qq) {
      const int q = w * 4 + qq;
      const int r = q * 8 + srow;
      lds16(Ab + (size_t)(m0 + r) * 128 + k0 + scol, &As[q * 512]);
      lds16(Qg + (size_t)r * 128 + k0 + scol, &Bq[q * 512]);
      lds16(Tg + (size_t)r * 128 + k0 + scol, &Bt[q * 512]);
    }
    __syncthreads();
#pragma unroll
    for (int ks = 0; ks < 2; ++ks) {
      short8 af[4], bq[4], bt[4];
      const int k8 = ks * 32 + hi * 8;
#pragma unroll
      for (int i = 0; i < 4; ++i) {
        af[i] = *(const short8*)&As[(wr * 64 + i * 16 + fro) * 64 + k8];
        bq[i] = *(const short8*)&Bq[(wc * 64 + i * 16 + fro) * 64 + k8];
        bt[i] = *(const short8*)&Bt[(wc * 64 + i * 16 + fro) * 64 + k8];
      }
#pragma unroll
      for (int i = 0; i < 4; ++i)
#pragma unroll
        for (int j = 0; j < 4; ++j) {
          aa[i][j] =
              __builtin_amdgcn_mfma_f32_16x16x32_bf16(af[i], bq[j], aa[i][j], 0, 0, 0);
          ab[i][j] =
              __builtin_amdgcn_mfma_f32_16x16x32_bf16(af[i], bt[j], ab[i][j], 0, 0, 0);
        }
    }
  }

  u16* Ls = sh;
  const int erow = t >> 4;
  const int ecol = (t & 15) * 8;
  const size_t obase0 = (size_t)b * 2097152 + (size_t)m0 * 2048 + dcol;
  short8 c8[8];

  __syncthreads();
#pragma unroll
  for (int i = 0; i < 4; ++i)
#pragma unroll
    for (int j = 0; j < 4; ++j)
#pragma unroll
      for (int g = 0; g < 4; ++g)
        Ls[(wr * 64 + i * 16 + hi * 4 + g) * 128 + wc * 64 + j * 16 + fro] =
            f2bf(aa[i][j][g]);
  __syncthreads();
#pragma unroll
  for (int it = 0; it < 8; ++it) {
    const int row = it * 16 + erow;
    const short8 a8 = *(const short8*)&Ls[row * 128 + ecol];
    c8[it] = *(const short8*)&O[obase0 + (size_t)row * 2048 + ecol];
    short8 p2;
#pragma unroll
    for (int kk = 0; kk < 8; ++kk)
      p2[kk] = (short)f2bf(bf2f((u16)c8[it][kk]) * bf2f((u16)a8[kk]));
    *(short8*)&O[obase0 + (size_t)row * 2048 + ecol + 512] = a8;
    *(short8*)&O[obase0 + (size_t)row * 2048 + ecol + 1024] = p2;
  }
  __syncthreads();
#pragma unroll
  for (int i = 0; i < 4; ++i)
#pragma unroll
    for (int j = 0; j < 4; ++j)
#pragma unroll
      for (int g = 0; g < 4; ++g)
        Ls[(wr * 64 + i * 16 + hi * 4 + g) * 128 + wc * 64 + j * 16 + fro] =
            f2bf(ab[i][j][g]);
  __syncthreads();
#pragma unroll
  for (int it = 0; it < 8; ++it) {
    const int row = it * 16 + erow;
    const short8 b8 = *(const short8*)&Ls[row * 128 + ecol];
    short8 p3;
#pragma unroll
    for (int kk = 0; kk < 8; ++kk)
      p3[kk] = (short)f2bf(bf2f((u16)c8[it][kk]) * bf2f((u16)b8[kk]));
    *(short8*)&O[obase0 + (size_t)row * 2048 + ecol + 1536] = p3;
  }
}

// ---- prep: C fp32 -> O chunk0 = C_t bf16 (ld 2048), Corig bf16, cbias atomic
__global__ __launch_bounds__(256) void prep_C(const float* __restrict__ C,
                                              const float* __restrict__ W0,
                                              u16* __restrict__ O,
                                              u16* __restrict__ Corig,
                                              float* __restrict__ cb) {
  __shared__ float L[64][65];
  __shared__ float P[4][64];
  const int b = blockIdx.z;
  const int d0 = blockIdx.y * 64;
  const int i0 = blockIdx.x * 64;
  const int t = threadIdx.x;
  const int cx = t & 63;
  const int rb = t >> 6;
  const float* Cb = C + ((size_t)b * 512 + d0) * 1024 + i0;
  float part = 0.f;
#pragma unroll
  for (int rr = 0; rr < 16; ++rr) {
    const int r = rb * 16 + rr;
    const float v = Cb[(size_t)r * 1024 + cx];
    L[r][cx] = v;
    part = fmaf(v, W0[d0 + r], part);
    Corig[((size_t)b * 512 + d0 + r) * 1024 + i0 + cx] = f2bf(v);
  }
  P[rb][cx] = part;
  __syncthreads();
#pragma unroll
  for (int rr = 0; rr < 16; ++rr) {
    const int il = rb * 16 + rr;
    O[((size_t)b * 1024 + i0 + il) * 2048 + d0 + cx] = f2bf(L[cx][il]);
  }
  if (rb == 0)
    atomicAdd(&cb[b * 1024 + i0 + cx], P[0][cx] + P[1][cx] + P[2][cx] + P[3][cx]);
}

// ---- prep: Q -> Qmb = (Q_t * w_m) bf16, Qorig bf16, qbias atomic -----------
__global__ __launch_bounds__(256) void prep_Q(const float* __restrict__ Q,
                                              const float* __restrict__ W0,
                                              u16* __restrict__ Qmb,
                                              u16* __restrict__ Qorig,
                                              float* __restrict__ qb) {
  __shared__ float L[64][65];
  __shared__ float P[4][64];
  const int b = blockIdx.z;
  const int d0 = blockIdx.y * 64;
  const int j0 = blockIdx.x * 64;
  const int t = threadIdx.x;
  const int cx = t & 63;
  const int rb = t >> 6;
  const float* Qb = Q + ((size_t)b * 512 + d0) * 128 + j0;
  float part = 0.f;
#pragma unroll
  for (int rr = 0; rr < 16; ++rr) {
    const int r = rb * 16 + rr;
    const float v = Qb[(size_t)r * 128 + cx];
    L[r][cx] = v;
    part = fmaf(v, W0[512 + d0 + r], part);
    Qorig[((size_t)b * 512 + d0 + r) * 128 + j0 + cx] = f2bf(v);
  }
  P[rb][cx] = part;
  __syncthreads();
  const float wm = W0[1024 + d0 + cx];
#pragma unroll
  for (int rr = 0; rr < 16; ++rr) {
    const int jl = rb * 16 + rr;
    Qmb[((size_t)b * 128 + j0 + jl) * 512 + d0 + cx] = f2bf(L[cx][jl] * wm);
  }
  if (rb == 0)
    atomicAdd(&qb[b * 128 + j0 + cx], P[0][cx] + P[1][cx] + P[2][cx] + P[3][cx]);
}

// ---- Wr fp32 -> bf16 -------------------------------------------------------
__global__ __launch_bounds__(256) void cvt_wr(const float* __restrict__ Wr,
                                              u16* __restrict__ Wrb) {
  const int idx = blockIdx.x * 256 + threadIdx.x;
  const float4 v = ((const float4*)Wr)[idx];
  short4v o;
  o[0] = (short)f2bf(v.x);
  o[1] = (short)f2bf(v.y);
  o[2] = (short)f2bf(v.z);
  o[3] = (short)f2bf(v.w);
  *(short4v*)&Wrb[(size_t)idx * 4] = o;
}

extern "C" void kernel_launch(void* const* d_in, const int* in_sizes, int n_in,
                              void* d_out, int out_size, void* d_ws, size_t ws_size,
                              hipStream_t stream) {
  (void)in_sizes; (void)n_in; (void)out_size;
  const float* C = (const float*)d_in[0];
  const float* Q = (const float*)d_in[1];
  const float* cm = (const float*)d_in[2];
  const float* qm = (const float*)d_in[3];
  const float* W0 = (const float*)d_in[4];
  const float* Wr = (const float*)d_in[5];
  float* out = (float*)d_out;

  if (ws_size < 405078016ull) return;  // ~386 MiB scratch

  char* p = (char*)d_ws;
  u16* O     = (u16*)(p);                    // (B,1024,2048) bf16 [C_t|A|C*A|C*Bm]
  u16* Corig = (u16*)(p + 268435456ull);     // (B,512,1024) bf16
  u16* Qmb   = (u16*)(p + 335544320ull);     // (B,128,512)  bf16
  u16* Qorig = (u16*)(p + 343932928ull);     // (B,512,128)  bf16
  u16* EunT  = (u16*)(p + 360710144ull);     // (B,128,1024) bf16 unnorm col-exp^T
  u16* Sbar  = (u16*)(p + 377487360ull);     // (B,1024,128) bf16
  u16* Tt    = (u16*)(p + 394264576ull);     // (B,512,128)  bf16
  u16* Wrb   = (u16*)(p + 402653184ull);     // (512,2048)   bf16
  float* cb  = (float*)(p + 404750336ull);   // (B,1024)
  float* qb  = (float*)(p + 405012480ull);   // (B,128)
  float* csum= (float*)(p + 405045248ull);   // (B,128)

  hipFuncSetAttribute((const void*)gemm_w,
                      hipFuncAttributeMaxDynamicSharedMemorySize, 67584);
  hipMemsetAsync(cb, 0, 327680, stream);  // cb + qb + csum contiguous

  cvt_wr<<<dim3(1024), dim3(256), 0, stream>>>(Wr, Wrb);
  prep_C<<<dim3(16, 8, 64), dim3(256), 0, stream>>>(C, W0, O, Corig, cb);
  prep_Q<<<dim3(2, 8, 64), dim3(256), 0, stream>>>(Q, W0, Qmb, Qorig, qb);

  // S-GEMM + fused row softmax + transposed unnormalized col-exp
  gemm_s<<<dim3(8, 1, 64), dim3(256), 0, stream>>>(O, Qmb, cb, qb, cm, qm,
                                                   Sbar, EunT, csum);

  // T^T scaled: Tt[b][d][j] = (EunT @ Corig^T)[j][d] / csum[b][j]
  gemm_t<<<dim3(1, 4, 64), dim3(256), 0, stream>>>(EunT, Corig, csum, Tt);

  // A & Bm in one kernel (K=128): chunks 1,2,3 of O with fused C_t products
  gemm_ab<<<dim3(8, 4, 64), dim3(256), 0, stream>>>(Sbar, Qorig, Tt, O);

  // R = Wr @ out^T : flat M=512, N=65536, K=2048; 128^2 quad-buf, 2 blk/CU
  gemm_w<<<dim3(2048), dim3(256), 67584, stream>>>(Wrb, O, out);
}

// Round 8
// 355.692 us; speedup vs baseline: 1.3057x; 1.3057x over previous
//
#include <hip/hip_runtime.h>
#include <hip/hip_bf16.h>

typedef unsigned short u16;
typedef __attribute__((ext_vector_type(8))) short short8;
typedef __attribute__((ext_vector_type(4))) short short4v;
typedef __attribute__((ext_vector_type(4))) float f32x4;

#define NEGV -1000000000000000.0f
#define SBAR() asm volatile("s_barrier" ::: "memory")

__device__ __forceinline__ u16 f2bf(float f) {
  unsigned u = __float_as_uint(f);
  unsigned r = (u + 0x7FFFu + ((u >> 16) & 1u)) >> 16;
  return (u16)r;
}
__device__ __forceinline__ float bf2f(u16 s) {
  return __uint_as_float(((unsigned)s) << 16);
}
__device__ __forceinline__ void lds16(const void* g, void* l) {
  __builtin_amdgcn_global_load_lds((const __attribute__((address_space(1))) void*)g,
                                   (__attribute__((address_space(3))) void*)l,
                                   16, 0, 0);
}

// ============ 256x256 GEMM, 16 waves (4Mx4N, 64x64/wave): out = Wrb @ O^T ===
// (r5 verified version, 148us.) LDS 160KB: A dbuf 2x32K + B 3-buf 3x32K.
// 2 phases/K-tile; stage A(t+1)@p0, B(t+2)@p1; uniform vmcnt(2)@p1.
__global__ __launch_bounds__(1024) void gemm8b(const u16* __restrict__ A,
                                               const u16* __restrict__ B,
                                               float* __restrict__ out) {
  extern __shared__ u16 lds[];
  const int bid = blockIdx.x;
  const int wg = (bid & 7) * 64 + (bid >> 3);  // m-pair shares B-tile on one XCD
  const int m0 = (wg & 1) * 256;
  const int n0 = (wg >> 1) * 256;
  const int tid = threadIdx.x;
  const int lane = tid & 63;
  const int w = tid >> 6;   // 0..15
  const int wr = w >> 2;    // 64-row band
  const int wc = w & 3;     // 64-col band
  const int fro = lane & 15;
  const int hi = lane >> 4;
  const int kx = fro & 7;
  const int sr = lane >> 3;
  const int sgc = ((lane & 7) ^ sr) << 3;  // pre-swizzled source col (elems)

  const u16* Ag = A + (size_t)m0 * 2048;
  const u16* Bg = B + (size_t)n0 * 2048;
  const int rA = wr * 64 + fro;
  const int rB = wc * 64 + fro;

  f32x4 acc[4][4] = {};

#define STG(gp, lp) \
  lds16((gp) + (size_t)(w * 8 + sr) * 2048 + sgc, (u16*)(lp) + w * 512)
#define RDF(base, row, k16) \
  (*(const short8*)&(base)[(size_t)(row) * 64 + (((k16) ^ kx) << 3)])

  // prologue: A0, B0, B1
  STG(Ag, lds);
  STG(Ag + 262144, lds + 8192);
  STG(Bg, lds + 32768);
  STG(Bg + 262144, lds + 32768 + 8192);
  STG(Bg + 64, lds + 49152);
  STG(Bg + 262144 + 64, lds + 49152 + 8192);
  asm volatile("s_waitcnt vmcnt(2)" ::: "memory");  // A0,B0 done; B1 in flight
  SBAR();

  const u16* Ac = lds;
  u16* An = lds + 16384;
  const u16* Bc = lds + 32768;   // B(t)
  const u16* Bn = lds + 49152;   // B(t+1)
  u16* Bs2 = lds + 65536;        // stage target B(t+2)

  for (int t = 0; t < 32; ++t) {
    const int kkA = (t < 31 ? t + 1 : 31) * 64;
    const int kkB = (t < 30 ? t + 2 : 31) * 64;
    short8 af[4], bf[4];

    // ---- phase 0 (ks=0): 8 ds_read; stage A(t+1); 16 MFMA
#pragma unroll
    for (int i = 0; i < 4; ++i) af[i] = RDF(Ac, rA + i * 16, hi);
#pragma unroll
    for (int j = 0; j < 4; ++j) bf[j] = RDF(Bc, rB + j * 16, hi);
    STG(Ag + kkA, An);
    STG(Ag + 262144 + kkA, An + 8192);
    SBAR();
    __builtin_amdgcn_s_setprio(1);
#pragma unroll
    for (int i = 0; i < 4; ++i)
#pragma unroll
      for (int j = 0; j < 4; ++j)
        acc[i][j] =
            __builtin_amdgcn_mfma_f32_16x16x32_bf16(af[i], bf[j], acc[i][j], 0, 0, 0);
    __builtin_amdgcn_s_setprio(0);
    SBAR();

    // ---- phase 1 (ks=1): 8 ds_read; stage B(t+2); vmcnt(2); 16 MFMA
#pragma unroll
    for (int i = 0; i < 4; ++i) af[i] = RDF(Ac, rA + i * 16, 4 + hi);
#pragma unroll
    for (int j = 0; j < 4; ++j) bf[j] = RDF(Bc, rB + j * 16, 4 + hi);
    STG(Bg + kkB, Bs2);
    STG(Bg + 262144 + kkB, Bs2 + 8192);
    asm volatile("s_waitcnt vmcnt(2)" ::: "memory");  // drain B(t+1), A(t+1)
    SBAR();
    __builtin_amdgcn_s_setprio(1);
#pragma unroll
    for (int i = 0; i < 4; ++i)
#pragma unroll
      for (int j = 0; j < 4; ++j)
        acc[i][j] =
            __builtin_amdgcn_mfma_f32_16x16x32_bf16(af[i], bf[j], acc[i][j], 0, 0, 0);
    __builtin_amdgcn_s_setprio(0);
    SBAR();

    // rotate buffers
    u16* tA = An; An = (u16*)Ac; Ac = tA;
    u16* tB = (u16*)Bc; Bc = Bn; Bn = Bs2; Bs2 = tB;
  }
  asm volatile("s_waitcnt vmcnt(0)" ::: "memory");

  // ---- epilogue: out[b][r][c], n = n0 + wc*64 + j*16 + fro
  const int crow = m0 + wr * 64 + hi * 4;
#pragma unroll
  for (int i = 0; i < 4; ++i)
#pragma unroll
    for (int j = 0; j < 4; ++j) {
      const int n = n0 + wc * 64 + j * 16 + fro;
      float* op = out + (size_t)(n >> 10) * 524288 + (n & 1023);
#pragma unroll
      for (int g = 0; g < 4; ++g)
        op[(size_t)(crow + i * 16 + g) * 1024] = acc[i][j][g];
    }
#undef STG
#undef RDF
}

// ============ T-GEMM: C_un = EunT(128x1024) @ Corig(512x1024)^T, then
// Tt[b][d][j] = C_un[j][d] / csum[b][j]  (transposed scaled store) ===========
__global__ __launch_bounds__(256) void gemm_t(const u16* __restrict__ A,
                                              const u16* __restrict__ B,
                                              const float* __restrict__ csum,
                                              u16* __restrict__ Tt) {
  __shared__ u16 As[128 * 64];
  __shared__ u16 Bs[128 * 64];
  const int b = blockIdx.z;
  const int n0 = blockIdx.y * 128;
  const u16* Ab = A + (size_t)b * 131072;
  const u16* Bb = B + (size_t)b * 524288;
  const int t = threadIdx.x;
  const int lane = t & 63;
  const int w = t >> 6;
  const int wr = w >> 1, wc = w & 1;
  const int srow = lane >> 3;
  const int scol = (lane & 7) * 8;

  f32x4 acc[4][4] = {};

  for (int k0 = 0; k0 < 1024; k0 += 64) {
    __syncthreads();
#pragma unroll
    for (int qq = 0; qq < 4; ++qq) {
      const int q = w * 4 + qq;
      const int r = q * 8 + srow;
      lds16(Ab + (size_t)r * 1024 + k0 + scol, &As[q * 512]);
      lds16(Bb + (size_t)(n0 + r) * 1024 + k0 + scol, &Bs[q * 512]);
    }
    __syncthreads();
#pragma unroll
    for (int ks = 0; ks < 2; ++ks) {
      short8 af[4], bg[4];
      const int fro = lane & 15;
      const int k8 = ks * 32 + (lane >> 4) * 8;
#pragma unroll
      for (int i = 0; i < 4; ++i)
        af[i] = *(const short8*)&As[(wr * 64 + i * 16 + fro) * 64 + k8];
#pragma unroll
      for (int i = 0; i < 4; ++i)
        bg[i] = *(const short8*)&Bs[(wc * 64 + i * 16 + fro) * 64 + k8];
#pragma unroll
      for (int i = 0; i < 4; ++i)
#pragma unroll
        for (int j = 0; j < 4; ++j)
          acc[i][j] =
              __builtin_amdgcn_mfma_f32_16x16x32_bf16(af[i], bg[j], acc[i][j], 0, 0, 0);
    }
  }

  const int col = lane & 15;
  const int r4 = (lane >> 4) * 4;
#pragma unroll
  for (int i = 0; i < 4; ++i)
#pragma unroll
    for (int g = 0; g < 4; ++g) {
      const int rr = wr * 64 + i * 16 + r4 + g;  // j index
      const float inv = 1.f / csum[b * 128 + rr];
#pragma unroll
      for (int j = 0; j < 4; ++j) {
        const int cc = n0 + wc * 64 + j * 16 + col;  // d index
        Tt[(size_t)b * 65536 + (size_t)cc * 128 + rr] = f2bf(acc[i][j][g] * inv);
      }
    }
}

// ============ S-GEMM + fused dual softmax + transposed-Eun epilogue =========
__global__ __launch_bounds__(256) void gemm_s(
    const u16* __restrict__ A, const u16* __restrict__ Bq,
    const float* __restrict__ cb, const float* __restrict__ qb,
    const float* __restrict__ cmask, const float* __restrict__ qmask,
    u16* __restrict__ Sbar, u16* __restrict__ EunT, float* __restrict__ csum) {
  __shared__ u16 As[128 * 64];
  __shared__ u16 Bs[128 * 64];
  __shared__ u16 Lt[128][136];
  __shared__ float rmaxs[2][128];
  __shared__ float rsums[2][128];
  __shared__ float cparts[2][128];
  const int b = blockIdx.z;
  const int m0 = blockIdx.x * 128;
  const u16* Ab = A + (size_t)b * 2097152;
  const u16* Bb = Bq + (size_t)b * 65536;
  const int t = threadIdx.x;
  const int lane = t & 63;
  const int w = t >> 6;
  const int wr = w >> 1, wc = w & 1;
  const int srow = lane >> 3;
  const int scol = (lane & 7) * 8;

  f32x4 acc[4][4] = {};

  for (int k0 = 0; k0 < 512; k0 += 64) {
    __syncthreads();
#pragma unroll
    for (int qq = 0; qq < 4; ++qq) {
      const int q = w * 4 + qq;
      const int r = q * 8 + srow;
      lds16(Ab + (size_t)(m0 + r) * 2048 + k0 + scol, &As[q * 512]);
      lds16(Bb + (size_t)r * 512 + k0 + scol, &Bs[q * 512]);
    }
    __syncthreads();
#pragma unroll
    for (int ks = 0; ks < 2; ++ks) {
      short8 af[4], bg[4];
      const int fro = lane & 15;
      const int k8 = ks * 32 + (lane >> 4) * 8;
#pragma unroll
      for (int i = 0; i < 4; ++i)
        af[i] = *(const short8*)&As[(wr * 64 + i * 16 + fro) * 64 + k8];
#pragma unroll
      for (int i = 0; i < 4; ++i)
        bg[i] = *(const short8*)&Bs[(wc * 64 + i * 16 + fro) * 64 + k8];
#pragma unroll
      for (int i = 0; i < 4; ++i)
#pragma unroll
        for (int j = 0; j < 4; ++j)
          acc[i][j] =
              __builtin_amdgcn_mfma_f32_16x16x32_bf16(af[i], bg[j], acc[i][j], 0, 0, 0);
    }
  }

  const int fro = lane & 15;
  const int hi = lane >> 4;
  float qv[4], qbv[4];
#pragma unroll
  for (int j = 0; j < 4; ++j) {
    const int cc = wc * 64 + j * 16 + fro;
    qv[j] = qmask[b * 128 + cc];
    qbv[j] = qb[b * 128 + cc];
  }
  float colp[4] = {0.f, 0.f, 0.f, 0.f};
#pragma unroll
  for (int i = 0; i < 4; ++i)
#pragma unroll
    for (int g = 0; g < 4; ++g) {
      const int rl = wr * 64 + i * 16 + hi * 4 + g;
      const float rb = cb[b * 1024 + m0 + rl];
      const float cv = cmask[b * 1024 + m0 + rl];
      const float coff = NEGV * (1.f - cv);
#pragma unroll
      for (int j = 0; j < 4; ++j) {
        const float v = acc[i][j][g] + rb + qbv[j];
        acc[i][j][g] = v;
        const float e = __expf(v * cv + coff);
        Lt[wc * 64 + j * 16 + fro][rl] = f2bf(e);
        colp[j] += e;
      }
    }
#pragma unroll
  for (int j = 0; j < 4; ++j) {
    colp[j] += __shfl_xor(colp[j], 16);
    colp[j] += __shfl_xor(colp[j], 32);
  }
  if (hi == 0)
#pragma unroll
    for (int j = 0; j < 4; ++j) cparts[wr][wc * 64 + j * 16 + fro] = colp[j];
  float rtmp[4][4];
#pragma unroll
  for (int i = 0; i < 4; ++i)
#pragma unroll
    for (int g = 0; g < 4; ++g) {
      float m = -3.4e38f;
#pragma unroll
      for (int j = 0; j < 4; ++j) {
        const float xm = acc[i][j][g] * qv[j] + NEGV * (1.f - qv[j]);
        acc[i][j][g] = xm;
        m = fmaxf(m, xm);
      }
#pragma unroll
      for (int o = 8; o; o >>= 1) m = fmaxf(m, __shfl_xor(m, o));
      rtmp[i][g] = m;
    }
  if (fro == 0)
#pragma unroll
    for (int i = 0; i < 4; ++i)
#pragma unroll
      for (int g = 0; g < 4; ++g)
        rmaxs[wc][wr * 64 + i * 16 + hi * 4 + g] = rtmp[i][g];
  __syncthreads();
  if (t < 128) atomicAdd(&csum[b * 128 + t], cparts[0][t] + cparts[1][t]);
  {
    const int jr = t >> 1;
    const int ih = (t & 1) * 64;
    u16* dst = EunT + (size_t)b * 131072 + (size_t)jr * 1024 + m0 + ih;
#pragma unroll
    for (int s = 0; s < 8; ++s)
      *(short8*)(dst + s * 8) = *(const short8*)&Lt[jr][ih + s * 8];
  }
#pragma unroll
  for (int i = 0; i < 4; ++i)
#pragma unroll
    for (int g = 0; g < 4; ++g) {
      const int rl = wr * 64 + i * 16 + hi * 4 + g;
      const float M = fmaxf(rmaxs[0][rl], rmaxs[1][rl]);
      float s = 0.f;
#pragma unroll
      for (int j = 0; j < 4; ++j) {
        const float p = __expf(acc[i][j][g] - M);
        acc[i][j][g] = p;
        s += p;
      }
#pragma unroll
      for (int o = 8; o; o >>= 1) s += __shfl_xor(s, o);
      rtmp[i][g] = s;
    }
  if (fro == 0)
#pragma unroll
    for (int i = 0; i < 4; ++i)
#pragma unroll
      for (int g = 0; g < 4; ++g)
        rsums[wc][wr * 64 + i * 16 + hi * 4 + g] = rtmp[i][g];
  __syncthreads();
#pragma unroll
  for (int i = 0; i < 4; ++i)
#pragma unroll
    for (int g = 0; g < 4; ++g) {
      const int rl = wr * 64 + i * 16 + hi * 4 + g;
      const float inv = 1.f / (rsums[0][rl] + rsums[1][rl]);
#pragma unroll
      for (int j = 0; j < 4; ++j)
        Sbar[((size_t)b * 1024 + m0 + rl) * 128 + wc * 64 + j * 16 + fro] =
            f2bf(acc[i][j][g] * inv);
    }
}

// ============ A+Bm GEMM v2: grid (dcol, b), Qo/Tt LDS-resident across all
// 8 m-tiles; Sbar double-buffered prefetch; swizzled [128][128] tiles.
// 512 thr (8 waves 2x4, 64x32/wave). LDS 160KB.
__global__ __launch_bounds__(512) void gemm_ab2(const u16* __restrict__ Sbar,
                                                const u16* __restrict__ Qo,
                                                const u16* __restrict__ Tt,
                                                u16* __restrict__ O) {
  extern __shared__ u16 sh[];
  u16* LQ = sh;             // 32KB Qo tile
  u16* LT = sh + 16384;     // 32KB Tt tile
  u16* Ls = sh + 65536;     // 32KB epilogue scratch
  const int dcol = blockIdx.x * 128;
  const int b = blockIdx.y;
  const int t = threadIdx.x;
  const int lane = t & 63;
  const int w = t >> 6;
  const int wr = w >> 2, wc = w & 3;
  const int fro = lane & 15, hi = lane >> 4;
  const int srow4 = t >> 4;   // 0..31
  const int sslot = t & 15;   // 16B slot

  const u16* Qg = Qo + (size_t)b * 65536 + (size_t)dcol * 128;
  const u16* Tg = Tt + (size_t)b * 65536 + (size_t)dcol * 128;
  const u16* Sg = Sbar + (size_t)b * 131072;

  // stage a 128x128 tile with slot^(row&7) pre-swizzled source (rule 21)
#define STG32(gp, lp)                                                         \
  {                                                                           \
    _Pragma("unroll") for (int ii = 0; ii < 4; ++ii) {                        \
      const int row_ = ii * 32 + srow4;                                       \
      lds16((gp) + (size_t)row_ * 128 + ((sslot ^ (row_ & 7)) << 3),          \
            (u16*)(lp) + ii * 4096 + t * 8);                                  \
    }                                                                         \
  }
#define RDS(base, row, kslot)                                                 \
  (*(const short8*)&(base)[(size_t)(row) * 128 + (((kslot) ^ ((row) & 7)) << 3)])

  STG32(Qg, LQ);
  STG32(Tg, LT);
  STG32(Sg, sh + 32768);
  asm volatile("s_waitcnt vmcnt(0)" ::: "memory");
  __syncthreads();

  for (int mm = 0; mm < 8; ++mm) {
    const u16* LSc = sh + 32768 + ((size_t)(mm & 1) << 14);
    u16* LSn = sh + 32768 + ((size_t)((mm + 1) & 1) << 14);
    if (mm < 7) STG32(Sg + (size_t)(mm + 1) * 16384, LSn);

    f32x4 aa[4][2] = {};
    f32x4 ab[4][2] = {};
#pragma unroll
    for (int ks = 0; ks < 4; ++ks) {
      short8 af[4], bq[2], bt[2];
#pragma unroll
      for (int i = 0; i < 4; ++i) {
        const int r = wr * 64 + i * 16 + fro;
        af[i] = RDS(LSc, r, ks * 4 + hi);
      }
#pragma unroll
      for (int j = 0; j < 2; ++j) {
        const int r = wc * 32 + j * 16 + fro;
        bq[j] = RDS(LQ, r, ks * 4 + hi);
        bt[j] = RDS(LT, r, ks * 4 + hi);
      }
#pragma unroll
      for (int i = 0; i < 4; ++i)
#pragma unroll
        for (int j = 0; j < 2; ++j) {
          aa[i][j] =
              __builtin_amdgcn_mfma_f32_16x16x32_bf16(af[i], bq[j], aa[i][j], 0, 0, 0);
          ab[i][j] =
              __builtin_amdgcn_mfma_f32_16x16x32_bf16(af[i], bt[j], ab[i][j], 0, 0, 0);
        }
    }

    // ---- epilogue for this m-tile (chunk1=A, chunk2=C*A, chunk3=C*Bm)
    const size_t obase = (size_t)b * 2097152 + (size_t)mm * 262144 + dcol;
    __syncthreads();  // also drains the prefetch (compiler-emitted waitcnt)
#pragma unroll
    for (int i = 0; i < 4; ++i)
#pragma unroll
      for (int j = 0; j < 2; ++j)
#pragma unroll
        for (int g = 0; g < 4; ++g)
          Ls[(wr * 64 + i * 16 + hi * 4 + g) * 128 + wc * 32 + j * 16 + fro] =
              f2bf(aa[i][j][g]);
    __syncthreads();
    short8 c8[4];
#pragma unroll
    for (int it = 0; it < 4; ++it) {
      const int row = it * 32 + srow4;
      const short8 a8 = *(const short8*)&Ls[row * 128 + sslot * 8];
      c8[it] = *(const short8*)&O[obase + (size_t)row * 2048 + sslot * 8];
      short8 p2;
#pragma unroll
      for (int k = 0; k < 8; ++k)
        p2[k] = (short)f2bf(bf2f((u16)c8[it][k]) * bf2f((u16)a8[k]));
      *(short8*)&O[obase + (size_t)row * 2048 + sslot * 8 + 512] = a8;
      *(short8*)&O[obase + (size_t)row * 2048 + sslot * 8 + 1024] = p2;
    }
    __syncthreads();
#pragma unroll
    for (int i = 0; i < 4; ++i)
#pragma unroll
      for (int j = 0; j < 2; ++j)
#pragma unroll
        for (int g = 0; g < 4; ++g)
          Ls[(wr * 64 + i * 16 + hi * 4 + g) * 128 + wc * 32 + j * 16 + fro] =
              f2bf(ab[i][j][g]);
    __syncthreads();
#pragma unroll
    for (int it = 0; it < 4; ++it) {
      const int row = it * 32 + srow4;
      const short8 b8 = *(const short8*)&Ls[row * 128 + sslot * 8];
      short8 p3;
#pragma unroll
      for (int k = 0; k < 8; ++k)
        p3[k] = (short)f2bf(bf2f((u16)c8[it][k]) * bf2f((u16)b8[k]));
      *(short8*)&O[obase + (size_t)row * 2048 + sslot * 8 + 1536] = p3;
    }
    __syncthreads();
  }
#undef STG32
#undef RDS
}

// ---- prep: C fp32 -> O chunk0 = C_t bf16 (ld 2048), Corig bf16, cbias atomic
__global__ __launch_bounds__(256) void prep_C(const float* __restrict__ C,
                                              const float* __restrict__ W0,
                                              u16* __restrict__ O,
                                              u16* __restrict__ Corig,
                                              float* __restrict__ cb) {
  __shared__ float L[64][65];
  __shared__ float P[4][64];
  const int b = blockIdx.z;
  const int d0 = blockIdx.y * 64;
  const int i0 = blockIdx.x * 64;
  const int t = threadIdx.x;
  const int cx = t & 63;
  const int rb = t >> 6;
  const float* Cb = C + ((size_t)b * 512 + d0) * 1024 + i0;
  float part = 0.f;
#pragma unroll
  for (int rr = 0; rr < 16; ++rr) {
    const int r = rb * 16 + rr;
    const float v = Cb[(size_t)r * 1024 + cx];
    L[r][cx] = v;
    part = fmaf(v, W0[d0 + r], part);
    Corig[((size_t)b * 512 + d0 + r) * 1024 + i0 + cx] = f2bf(v);
  }
  P[rb][cx] = part;
  __syncthreads();
#pragma unroll
  for (int rr = 0; rr < 16; ++rr) {
    const int il = rb * 16 + rr;
    O[((size_t)b * 1024 + i0 + il) * 2048 + d0 + cx] = f2bf(L[cx][il]);
  }
  if (rb == 0)
    atomicAdd(&cb[b * 1024 + i0 + cx], P[0][cx] + P[1][cx] + P[2][cx] + P[3][cx]);
}

// ---- prep: Q -> Qmb = (Q_t * w_m) bf16, Qorig bf16, qbias atomic -----------
__global__ __launch_bounds__(256) void prep_Q(const float* __restrict__ Q,
                                              const float* __restrict__ W0,
                                              u16* __restrict__ Qmb,
                                              u16* __restrict__ Qorig,
                                              float* __restrict__ qb) {
  __shared__ float L[64][65];
  __shared__ float P[4][64];
  const int b = blockIdx.z;
  const int d0 = blockIdx.y * 64;
  const int j0 = blockIdx.x * 64;
  const int t = threadIdx.x;
  const int cx = t & 63;
  const int rb = t >> 6;
  const float* Qb = Q + ((size_t)b * 512 + d0) * 128 + j0;
  float part = 0.f;
#pragma unroll
  for (int rr = 0; rr < 16; ++rr) {
    const int r = rb * 16 + rr;
    const float v = Qb[(size_t)r * 128 + cx];
    L[r][cx] = v;
    part = fmaf(v, W0[512 + d0 + r], part);
    Qorig[((size_t)b * 512 + d0 + r) * 128 + j0 + cx] = f2bf(v);
  }
  P[rb][cx] = part;
  __syncthreads();
  const float wm = W0[1024 + d0 + cx];
#pragma unroll
  for (int rr = 0; rr < 16; ++rr) {
    const int jl = rb * 16 + rr;
    Qmb[((size_t)b * 128 + j0 + jl) * 512 + d0 + cx] = f2bf(L[cx][jl] * wm);
  }
  if (rb == 0)
    atomicAdd(&qb[b * 128 + j0 + cx], P[0][cx] + P[1][cx] + P[2][cx] + P[3][cx]);
}

// ---- Wr fp32 -> bf16 -------------------------------------------------------
__global__ __launch_bounds__(256) void cvt_wr(const float* __restrict__ Wr,
                                              u16* __restrict__ Wrb) {
  const int idx = blockIdx.x * 256 + threadIdx.x;
  const float4 v = ((const float4*)Wr)[idx];
  short4v o;
  o[0] = (short)f2bf(v.x);
  o[1] = (short)f2bf(v.y);
  o[2] = (short)f2bf(v.z);
  o[3] = (short)f2bf(v.w);
  *(short4v*)&Wrb[(size_t)idx * 4] = o;
}

extern "C" void kernel_launch(void* const* d_in, const int* in_sizes, int n_in,
                              void* d_out, int out_size, void* d_ws, size_t ws_size,
                              hipStream_t stream) {
  (void)in_sizes; (void)n_in; (void)out_size;
  const float* C = (const float*)d_in[0];
  const float* Q = (const float*)d_in[1];
  const float* cm = (const float*)d_in[2];
  const float* qm = (const float*)d_in[3];
  const float* W0 = (const float*)d_in[4];
  const float* Wr = (const float*)d_in[5];
  float* out = (float*)d_out;

  if (ws_size < 405078016ull) return;  // ~386 MiB scratch

  char* p = (char*)d_ws;
  u16* O     = (u16*)(p);                    // (B,1024,2048) bf16 [C_t|A|C*A|C*Bm]
  u16* Corig = (u16*)(p + 268435456ull);     // (B,512,1024) bf16
  u16* Qmb   = (u16*)(p + 335544320ull);     // (B,128,512)  bf16
  u16* Qorig = (u16*)(p + 343932928ull);     // (B,512,128)  bf16
  u16* EunT  = (u16*)(p + 360710144ull);     // (B,128,1024) bf16 unnorm col-exp^T
  u16* Sbar  = (u16*)(p + 377487360ull);     // (B,1024,128) bf16
  u16* Tt    = (u16*)(p + 394264576ull);     // (B,512,128)  bf16
  u16* Wrb   = (u16*)(p + 402653184ull);     // (512,2048)   bf16
  float* cb  = (float*)(p + 404750336ull);   // (B,1024)
  float* qb  = (float*)(p + 405012480ull);   // (B,128)
  float* csum= (float*)(p + 405045248ull);   // (B,128)

  (void)hipFuncSetAttribute((const void*)gemm8b,
                            hipFuncAttributeMaxDynamicSharedMemorySize, 163840);
  (void)hipFuncSetAttribute((const void*)gemm_ab2,
                            hipFuncAttributeMaxDynamicSharedMemorySize, 163840);
  (void)hipMemsetAsync(cb, 0, 327680, stream);  // cb + qb + csum contiguous

  cvt_wr<<<dim3(1024), dim3(256), 0, stream>>>(Wr, Wrb);
  prep_C<<<dim3(16, 8, 64), dim3(256), 0, stream>>>(C, W0, O, Corig, cb);
  prep_Q<<<dim3(2, 8, 64), dim3(256), 0, stream>>>(Q, W0, Qmb, Qorig, qb);

  // S-GEMM + fused row softmax + transposed unnormalized col-exp
  gemm_s<<<dim3(8, 1, 64), dim3(256), 0, stream>>>(O, Qmb, cb, qb, cm, qm,
                                                   Sbar, EunT, csum);

  // T^T scaled: Tt[b][d][j] = (EunT @ Corig^T)[j][d] / csum[b][j]
  gemm_t<<<dim3(1, 4, 64), dim3(256), 0, stream>>>(EunT, Corig, csum, Tt);

  // A & Bm: Qo/Tt LDS-resident, loop m-tiles, chunks 1,2,3 of O
  gemm_ab2<<<dim3(4, 64), dim3(512), 163840, stream>>>(Sbar, Qorig, Tt, O);

  // R = Wr @ out^T : flat M=512, N=65536, K=2048; 16-wave 256^2
  gemm8b<<<dim3(512), dim3(1024), 163840, stream>>>(Wrb, O, out);
}